// Round 12
// baseline (799.137 us; speedup 1.0000x reference)
//
#include <hip/hip_runtime.h>
#include <hip/hip_fp16.h>

// Problem constants
#define NQ   2048      // N_LC == N_TE
#define NB   4         // batch
#define DD   256       // feature dim
#define M1   2049      // NQ + dustbin
#define STR  2064      // padded row stride (fp16 elems for E, bytes for E8/ET8)
#define UVS  1088      // u/v vector stride in dwords (1024 packed-fp16 pairs + dust + pad)
#define SINK_ITERS 100
#define PNWG 256       // persistent WGs (64 per batch) — 1/CU co-residency
#define PTPB 1024      // 16 waves per WG

typedef __attribute__((ext_vector_type(8))) short short8;
typedef __attribute__((ext_vector_type(4))) float floatx4;
typedef _Float16 h2 __attribute__((ext_vector_type(2)));

__device__ __forceinline__ unsigned short f2bf(float f) {
  unsigned u = __float_as_uint(f);
  u += 0x7FFF + ((u >> 16) & 1);   // round-to-nearest-even
  return (unsigned short)(u >> 16);
}

// fp32 -> fp8 e5m2 (OCP): e5m2 == top byte of IEEE half, RN
__device__ __forceinline__ unsigned char f2fp8(float f) {
  unsigned short u = __half_as_ushort(__float2half(f));
  return (unsigned char)((u + 0x7F + ((u >> 8) & 1)) >> 8);
}

__device__ __forceinline__ h2 as_h2(unsigned x) {
  union { unsigned u; h2 h; } c; c.u = x; return c.h;
}

// ---------------- merged: fp32->bf16 convert (6 inputs) + E dustbin fill +
//                  ev init (packed fp16 4096.0 pairs) + barrier zero ----------
// cvt part: 4352 blocks (1114112 vec4 elems); fill part: 570 blocks
__global__ void k_prep(const float* __restrict__ x_lc, const float* __restrict__ x_te,
                       const float* __restrict__ w1lc, const float* __restrict__ w2lc,
                       const float* __restrict__ w1te, const float* __restrict__ w2te,
                       unsigned short* __restrict__ Xlc, unsigned short* __restrict__ Xte,
                       unsigned short* __restrict__ Wb, __half* __restrict__ E,
                       const float* __restrict__ alphaPtr, unsigned* __restrict__ ev,
                       unsigned* __restrict__ bar) {
  const int NX4 = (NB * NQ * DD) / 4;   // 524288
  const int NW4 = (DD * DD) / 4;        // 16384
  const int bx = blockIdx.x;
  if (bx < 4352) {
    int i4 = bx * 256 + threadIdx.x;
    const float* src; unsigned short* dst; int off;
    if (i4 < NX4)            { src = x_lc; dst = Xlc; off = i4; }
    else if (i4 < 2 * NX4)   { src = x_te; dst = Xte; off = i4 - NX4; }
    else {
      int k = i4 - 2 * NX4;
      int seg = k / NW4;
      off = k - seg * NW4;
      src = (seg == 0) ? w1lc : (seg == 1) ? w2lc : (seg == 2) ? w1te : w2te;
      dst = Wb + seg * 65536;
    }
    float4 f = ((const float4*)src)[off];
    ushort4 o;
    o.x = f2bf(f.x); o.y = f2bf(f.y); o.z = f2bf(f.z); o.w = f2bf(f.w);
    ((ushort4*)dst)[off] = o;
    return;
  }
  // fill part
  const int idx = (bx - 4352) * 256 + threadIdx.x;
  const float ea = __expf(*alphaPtr);
  const int n1 = NB * NQ * 16;          // E rows 0..2047, cols 2048..2063
  if (idx < n1) {
    int b = idx / (NQ * 16);
    int rr = idx - b * NQ * 16;
    int i = rr >> 4;
    int j = 2048 + (rr & 15);
    E[((long)b * M1 + i) * STR + j] = (j == 2048) ? __float2half(ea) : __float2half(0.f);
    return;
  }
  int k = idx - n1;
  if (k < NB * STR) {                   // E dustbin row
    int b = k / STR;
    int j = k - b * STR;
    E[((long)b * M1 + 2048) * STR + j] = (j <= 2048) ? __float2half(ea) : __float2half(0.f);
    return;
  }
  int m = k - NB * STR;
  if (m < NB * UVS) {                   // ev init: v_s = 4096.0 (packed fp16), dust fp32
    int bloc = m / UVS;
    int slot = m - bloc * UVS;
    ev[m] = (slot < 1024) ? 0x6C006C00u             // fp16(4096,4096)
          : (slot == 1024 ? __float_as_uint(4096.f) : 0u);
    return;
  }
  int q = m - NB * UVS;
  if (q < 2048) bar[q] = 0u;            // 4 batches x {cnt, gen} lines
}

// ---------------- bf16 MFMA GEMM, C = A * B^T (both [rows x K] row-major) ----
// MODE 0: +bias, relu -> bf16          (MLP layer 1; bias selected by blockIdx.z)
// MODE 1: +bias       -> bf16          (MLP layer 2; bias selected by blockIdx.z)
// MODE 2: *1/16, clamp, exp -> fp16 E + fp8 E8 + TRANSPOSED fp8 ET8 (packed 4B)
template<int MODE>
__global__ __launch_bounds__(256, 2)
void k_gemm_bt(const unsigned short* __restrict__ A,
               const unsigned short* __restrict__ Bt,
               void* __restrict__ Out, void* __restrict__ Out8, void* __restrict__ OutT8,
               const float* __restrict__ bias, const float* __restrict__ bias2,
               int K, long aBatch, long bBatch, long oBatch, int ostride)
{
  __shared__ __align__(16) unsigned short lA[128 * 32];
  __shared__ __align__(16) unsigned short lB[128 * 32];
  const int tid  = threadIdx.x;
  const int lane = tid & 63;
  const int w    = tid >> 6;
  const int wm   = (w >> 1) * 64;
  const int wn   = (w & 1) * 64;
  const long bz  = blockIdx.z;
  const unsigned short* Ab = A  + bz * aBatch + (long)blockIdx.y * 128 * K;
  const unsigned short* Bb = Bt + bz * bBatch + (long)blockIdx.x * 128 * K;
  const float* bp = (bz == 0) ? bias : bias2;

  floatx4 acc[4][4];
  #pragma unroll
  for (int i = 0; i < 4; i++)
    #pragma unroll
    for (int j = 0; j < 4; j++) acc[i][j] = (floatx4){0.f, 0.f, 0.f, 0.f};

  for (int kt = 0; kt < K; kt += 32) {
    __syncthreads();
    #pragma unroll
    for (int s0 = 0; s0 < 512; s0 += 256) {
      int s = s0 + tid;
      int row = s >> 2, part = s & 3;
      ((uint4*)lA)[s] = *(const uint4*)(Ab + (long)row * K + kt + part * 8);
      ((uint4*)lB)[s] = *(const uint4*)(Bb + (long)row * K + kt + part * 8);
    }
    __syncthreads();
    const int kq = (lane >> 4) * 8;
    const int rl = lane & 15;
    short8 af[4], bf[4];
    #pragma unroll
    for (int t = 0; t < 4; t++) {
      af[t] = *(const short8*)(lA + (wm + t * 16 + rl) * 32 + kq);
      bf[t] = *(const short8*)(lB + (wn + t * 16 + rl) * 32 + kq);
    }
    #pragma unroll
    for (int i = 0; i < 4; i++)
      #pragma unroll
      for (int j = 0; j < 4; j++)
        acc[i][j] = __builtin_amdgcn_mfma_f32_16x16x32_bf16(af[i], bf[j], acc[i][j], 0, 0, 0);
  }

  // epilogue — C/D layout: col = lane&15, row = (lane>>4)*4 + reg
  const int cl = lane & 15, qd = lane >> 4;
  #pragma unroll
  for (int i = 0; i < 4; i++)
    #pragma unroll
    for (int j = 0; j < 4; j++) {
      const int col = blockIdx.x * 128 + wn + j * 16 + cl;
      const float bcol = (MODE >= 2) ? 0.f : bp[col];
      const long rowbase = (long)blockIdx.y * 128 + wm + i * 16 + qd * 4;
      unsigned pk = 0;
      #pragma unroll
      for (int r = 0; r < 4; r++) {
        const long row = rowbase + r;
        float v = acc[i][j][r];
        if (MODE == 0) {
          v += bcol; v = v > 0.f ? v : 0.f;
          ((unsigned short*)Out)[bz * oBatch + row * ostride + col] = f2bf(v);
        } else if (MODE == 1) {
          v += bcol;
          ((unsigned short*)Out)[bz * oBatch + row * ostride + col] = f2bf(v);
        } else {
          v *= 0.0625f;                       // 1/sqrt(256)
          v = fminf(fmaxf(v, -15.f), 10.9f);  // e^10.9 = 54k < e5m2 max 57344
          float e = __expf(v);
          const long idx = bz * oBatch + row * ostride + col;
          ((__half*)Out)[idx] = __float2half(e);
          unsigned char f8 = f2fp8(e);
          ((unsigned char*)Out8)[idx] = f8;
          pk |= (unsigned)f8 << (8 * r);      // rows rowbase..rowbase+3 contiguous in ET8
        }
      }
      if (MODE == 2) {
        // transposed packed store: ET8[col][rowbase..rowbase+3], 4B aligned
        *(unsigned*)((unsigned char*)OutT8 + bz * oBatch + (long)col * ostride + rowbase) = pk;
      }
    }
}

// ---------------- agent-scope relaxed helpers (NO cache invalidates) ---------
__device__ __forceinline__ void st_u32_agent(unsigned* p, unsigned v) {
  __hip_atomic_store(p, v, __ATOMIC_RELAXED, __HIP_MEMORY_SCOPE_AGENT);
}
__device__ __forceinline__ unsigned ld_u32_agent(const unsigned* p) {
  return __hip_atomic_load(p, __ATOMIC_RELAXED, __HIP_MEMORY_SCOPE_AGENT);
}

__device__ __forceinline__ float wave_sum(float s) {
  #pragma unroll
  for (int o = 32; o; o >>= 1) s += __shfl_xor(s, o);
  return s;
}

// dot of 16 fp8(e5m2) row bytes (uint4) with 16 fp16 weights (8 h2 dwords).
// e5m2 -> fp16 is exact: byte<<8. v_perm builds 2 halves/dword in 1 op;
// v_dot2_f32_f16 does 2 MACs with f32 accumulate.
__device__ __forceinline__ float dot16e5(uint4 hv, const unsigned* wp, float s) {
  const unsigned* u = (const unsigned*)&hv;
#if __has_builtin(__builtin_amdgcn_fdot2) && __has_builtin(__builtin_amdgcn_perm)
  #pragma unroll
  for (int q = 0; q < 4; q++) {
    unsigned lo = __builtin_amdgcn_perm(u[q], 0u, 0x05000400u);  // halves b0<<8, b1<<8
    unsigned hi = __builtin_amdgcn_perm(u[q], 0u, 0x07000600u);  // halves b2<<8, b3<<8
    s = __builtin_amdgcn_fdot2(as_h2(lo), as_h2(wp[2 * q]),     s, false);
    s = __builtin_amdgcn_fdot2(as_h2(hi), as_h2(wp[2 * q + 1]), s, false);
  }
#else
  const unsigned char* p = (const unsigned char*)&hv;
  #pragma unroll
  for (int t = 0; t < 16; t++) {
    unsigned short he = (unsigned short)p[t] << 8;
    unsigned wdw = wp[t >> 1];
    unsigned short hw = (t & 1) ? (unsigned short)(wdw >> 16) : (unsigned short)(wdw & 0xFFFF);
    s += __half2float(*reinterpret_cast<__half*>(&he)) *
         __half2float(*reinterpret_cast<__half*>(&hw));
  }
#endif
  return s;
}

// ---------------- persistent Sinkhorn, plain launch (NOT cooperative) --------
// R10 core (789us total): fp8 rows LDS-pinned (FETCH 43MB), 64 WGs/batch,
// perm+fdot2 dots with stride-9 fp16 weights, flat arrive + last-man gen
// broadcast barrier with gen prefetch.
//
// R11 change: u/v vectors are PACKED fp16 PAIRS (scaled x4096), stored by the
// producer: lane0's two row-values (rows r0, r0+1 — an even pair) pack into
// ONE dword store; staging is a raw 4B agent load + LDS store, ZERO
// conversion VALU. The dots consume the exact same fp16 values as R10 (the
// rounding point just moved from consumer to producer). Scaled algebra
// (R7/R10-proven): u_s = 4096/(a_s + ea*d_s); dust_s = 8388608/(ea*(S_s+d_s));
// k_final: out = E*u_s*v_s/4096. Vector payload halves to 4KB + fp32 dust.
// Codegen shape rules preserved: no lambda, tid0-only scalar poll, row reads
// after the staging sync.
__global__ __launch_bounds__(PTPB, 4)
void k_sink(const unsigned char* __restrict__ E8, const unsigned char* __restrict__ ET8,
            unsigned* __restrict__ eu, unsigned* __restrict__ ev,
            const float* __restrict__ alphaPtr, unsigned* __restrict__ bar)
{
  __shared__ __align__(16) unsigned char rows[131072];  // [wave][E|ET][2 rows][2048]
  __shared__ __align__(16) unsigned svh[1160];          // 2 chunks x 576 h2-dwords (pad/8)
  __shared__ float sdust;                               // staged dust (scaled, fp32)
  const int tid  = threadIdx.x;
  const int wg   = blockIdx.x;
  const int b    = wg >> 6;          // batch 0..3
  const int g    = wg & 63;          // group within batch
  const int wv   = tid >> 6;         // wave 0..15
  const int lane = tid & 63;
  const int r0   = (g * 16 + wv) * 2;   // rows r0, r0+1 in [0, 2048)
  const float ea = __expf(alphaPtr[0]);
  const unsigned char* E8r  = E8  + ((long)b * M1 + r0) * STR;
  const unsigned char* ET8r = ET8 + ((long)b * M1 + r0) * STR;
  unsigned* ub = eu + b * UVS;
  unsigned* vb = ev + b * UVS;
  unsigned* cnt = bar + b * 64;       // per-batch arrive counter
  unsigned* gen = bar + b * 64 + 32;  // release word, separate 128B line
  const bool dustwave = (g == 63) && (wv == 15);
  // staging slot: thread t holds dword t (cols 2t, 2t+1); chunk = t>>9
  const int sslot = (tid >> 9) * 576 + (tid & 511) + ((tid & 511) >> 3);

  // prologue: pin this wave's 4 rows in LDS (read once from L2/HBM)
  {
    uint4* dw = (uint4*)(rows + wv * 8192);
    dw[lane]       = *(const uint4*)(E8r  +        lane * 16);
    dw[64 + lane]  = *(const uint4*)(E8r  + 1024 + lane * 16);
    dw[128 + lane] = *(const uint4*)(E8r  + STR  +        lane * 16);
    dw[192 + lane] = *(const uint4*)(E8r  + STR  + 1024 + lane * 16);
    dw[256 + lane] = *(const uint4*)(ET8r +        lane * 16);
    dw[320 + lane] = *(const uint4*)(ET8r + 1024 + lane * 16);
    dw[384 + lane] = *(const uint4*)(ET8r + STR  +        lane * 16);
    dw[448 + lane] = *(const uint4*)(ET8r + STR  + 1024 + lane * 16);
  }

  const unsigned* w0 = svh + 9 * lane;          // chunk 0: lane's 8 h2 dwords
  const unsigned* w1 = svh + 576 + 9 * lane;    // chunk 1
  const unsigned ONES2 = 0x3C003C00u;           // fp16 (1.0, 1.0)

  unsigned phase = 0;
  for (int it = 0; it < 2 * SINK_ITERS; ++it) {
    const unsigned* vin = (it & 1) ? ub : vb;
    unsigned*      vout = (it & 1) ? vb : ub;

    // stage vin -> LDS (raw packed dword, one 4B sc1 load per thread)
    {
      unsigned pkv = ld_u32_agent(vin + tid);
      svh[sslot] = pkv;
      if (tid == 0) sdust = __uint_as_float(ld_u32_agent(vin + 1024));
    }
    __syncthreads();

    // two fp8 rows per wave from the LDS row cache
    const unsigned char* Rl = rows + wv * 8192 + ((it & 1) << 12);
    uint4 h0c0 = *(const uint4*)(Rl +        lane * 16);
    uint4 h0c1 = *(const uint4*)(Rl + 1024 + lane * 16);
    uint4 h1c0 = *(const uint4*)(Rl + 2048 + lane * 16);
    uint4 h1c1 = *(const uint4*)(Rl + 3072 + lane * 16);
    float a0 = dot16e5(h0c1, w1, dot16e5(h0c0, w0, 0.f));
    float a1 = dot16e5(h1c1, w1, dot16e5(h1c0, w0, 0.f));
    a0 = wave_sum(a0);
    a1 = wave_sum(a1);
    if (lane == 0) {
      const float wd = ea * sdust;               // dustbin column (scaled)
      float u0 = 4096.f / (a0 + wd);
      float u1 = 4096.f / (a1 + wd);
      unsigned pk = ((unsigned)__half_as_ushort(__float2half(u1)) << 16)
                  |  (unsigned)__half_as_ushort(__float2half(u0));
      st_u32_agent(vout + (r0 >> 1), pk);
    }

    // dustbin row analytic: dust_s = 8388608 / (ea * (S_s + d_s))
    if (dustwave) {
      float s = 0.f;
#if __has_builtin(__builtin_amdgcn_fdot2)
      #pragma unroll
      for (int k = 0; k < 8; k++) s = __builtin_amdgcn_fdot2(as_h2(w0[k]), as_h2(ONES2), s, false);
      #pragma unroll
      for (int k = 0; k < 8; k++) s = __builtin_amdgcn_fdot2(as_h2(w1[k]), as_h2(ONES2), s, false);
#else
      #pragma unroll
      for (int k = 0; k < 8; k++) {
        unsigned a = w0[k], c = w1[k];
        unsigned short x0 = (unsigned short)a, x1 = (unsigned short)(a >> 16);
        unsigned short y0 = (unsigned short)c, y1 = (unsigned short)(c >> 16);
        s += __half2float(*reinterpret_cast<__half*>(&x0)) + __half2float(*reinterpret_cast<__half*>(&x1))
           + __half2float(*reinterpret_cast<__half*>(&y0)) + __half2float(*reinterpret_cast<__half*>(&y1));
      }
#endif
      s = wave_sum(s);
      if (lane == 0)
        st_u32_agent(vout + 1024, __float_as_uint(8388608.f / (ea * (s + sdust))));
    }

    // ---- per-batch barrier: flat arrive + last-man gen broadcast ----
    ++phase;
    __syncthreads();   // drains vmcnt: this WG's sc1 stores are at LLC
    if (tid == 0) {
      unsigned gpre = ld_u32_agent(gen);   // prefetch: overlaps the RMW hop
      unsigned old = __hip_atomic_fetch_add(cnt, 1u, __ATOMIC_RELAXED, __HIP_MEMORY_SCOPE_AGENT);
      if (old == phase * 64u - 1u) {
        __hip_atomic_store(gen, phase, __ATOMIC_RELAXED, __HIP_MEMORY_SCOPE_AGENT);
      } else {
        while (gpre < phase) {
          __builtin_amdgcn_s_sleep(1);
          gpre = ld_u32_agent(gen);
        }
      }
    }
    __syncthreads();
  }
}

// ---------------- finalize: out = E * u_s * v_s / 4096 (fp16 E, packed u/v) --
__global__ void k_final(const __half* __restrict__ E, const unsigned* __restrict__ eu,
                        const unsigned* __restrict__ ev, float* __restrict__ out) {
  const int wvb = blockIdx.x;     // NB * M1 rows
  const int b = wvb / M1;
  const int i = wvb - b * M1;
  const __half* R = E + ((long)b * M1 + i) * STR;
  const unsigned* ub = eu + b * UVS;
  const unsigned* vb = ev + b * UVS;
  float ui;
  if (i < 2048) {
    unsigned d = ub[i >> 1];
    unsigned short h = (i & 1) ? (unsigned short)(d >> 16) : (unsigned short)(d & 0xFFFF);
    ui = __half2float(*reinterpret_cast<const __half*>(&h));
  } else {
    ui = __uint_as_float(ub[1024]);
  }
  ui *= (1.f / 4096.f);
  float* orow = out + ((long)b * M1 + i) * M1;
  for (int j = threadIdx.x; j < M1; j += blockDim.x) {
    float vj;
    if (j < 2048) {
      unsigned d = vb[j >> 1];
      unsigned short h = (j & 1) ? (unsigned short)(d >> 16) : (unsigned short)(d & 0xFFFF);
      vj = __half2float(*reinterpret_cast<const __half*>(&h));
    } else {
      vj = __uint_as_float(vb[1024]);
    }
    orow[j] = __half2float(R[j]) * ui * vj;
  }
}

// ---------------- launch -----------------------------------------------------
extern "C" void kernel_launch(void* const* d_in, const int* in_sizes, int n_in,
                              void* d_out, int out_size, void* d_ws, size_t ws_size,
                              hipStream_t stream) {
  const float* x_lc  = (const float*)d_in[0];
  const float* x_te  = (const float*)d_in[1];
  const float* W1_lc = (const float*)d_in[2];
  const float* b1_lc = (const float*)d_in[3];
  const float* W2_lc = (const float*)d_in[4];
  const float* b2_lc = (const float*)d_in[5];
  const float* W1_te = (const float*)d_in[6];
  const float* b1_te = (const float*)d_in[7];
  const float* W2_te = (const float*)d_in[8];
  const float* b2_te = (const float*)d_in[9];
  const float* alpha = (const float*)d_in[10];

  char* ws = (char*)d_ws;
  unsigned short* Xlc = (unsigned short*)(ws + 0);          //  4 MB (later reused as F1)
  unsigned short* Wb  = (unsigned short*)(ws + 8388608);    //  0.5 MB
  unsigned short* H   = (unsigned short*)(ws + 8912896);    //  8 MB (both MLP chains)
  unsigned short* F   = (unsigned short*)(ws + 0);          //  8 MB (F1 @0, F2 @4MB)
  __half* E  = (__half*)(ws + 21495808);                    // 33.83 MB fp16 (final)
  unsigned char* E8  = (unsigned char*)(ws + 55328896);     // 16.92 MB fp8 (sweep)
  unsigned char* ET8 = (unsigned char*)(ws + 72245440);     // 16.92 MB fp8 (transposed)
  unsigned* eu  = (unsigned*)(ws + 89161984);               // 4 x UVS dwords (packed fp16)
  unsigned* ev  = (unsigned*)(ws + 89195008);               // 4 x UVS dwords
  unsigned* bar = (unsigned*)(ws + 89228032);               // 8 KB barrier state

  unsigned short* Xte = Xlc + 2097152;   // ws + 4 MB

  // merged: cvt6 + E dustbin fill + ev init + barrier zero (one launch)
  // fill items: 131072 + 8256 + 4352 + 2048 = 145728 -> 570 blocks
  k_prep<<<4352 + 570, 256, 0, stream>>>(x_lc, x_te, W1_lc, W2_lc, W1_te, W2_te,
                                         Xlc, Xte, Wb, E, alpha, ev, bar);

  // MLPs: lc and te chains merged via blockIdx.z (z=0: lc, z=1: te).
  k_gemm_bt<0><<<dim3(2, 64, 2), 256, 0, stream>>>(Xlc, Wb,         H, nullptr, nullptr,
                                                   b1_lc, b1_te, DD, 2097152, 131072, 2097152, DD);
  k_gemm_bt<1><<<dim3(2, 64, 2), 256, 0, stream>>>(H,   Wb + 65536, F, nullptr, nullptr,
                                                   b2_lc, b2_te, DD, 2097152, 131072, 2097152, DD);

  // scores -> E (fp16) + E8 (fp8) + ET8 (fp8, transposed packed 4B), ONE GEMM
  unsigned short* F1 = F;
  unsigned short* F2 = F + 2097152;
  const long ab = (long)NQ * DD;        // 524288
  const long ob = (long)M1 * STR;       // 4229136 (elems for fp16, bytes for fp8)
  k_gemm_bt<2><<<dim3(16, 16, NB), 256, 0, stream>>>(F1, F2, E, E8, ET8,
                                                     nullptr, nullptr, DD, ab, ab, ob, STR);

  // persistent Sinkhorn: ONE plain launch, fixed 100 iterations
  k_sink<<<PNWG, PTPB, 0, stream>>>(E8, ET8, eu, ev, alpha, bar);

  // out = E * u_s * v_s / 4096
  k_final<<<NB * M1, 256, 0, stream>>>(E, eu, ev, (float*)d_out);
}